// Round 15
// baseline (144.500 us; speedup 1.0000x reference)
//
#include <hip/hip_runtime.h>
#include <hip/hip_bf16.h>
#include <stdint.h>

#define BB 8
#define CC 640
#define HWSZ 4096
#define RR 4
#define KD 160
#define VH 16
#define VW 16
#define KW 1280      // Wbf row stride (full Wg row)
#define KX 640       // GEMM K (W1 half)
#define TEMP 0.1f

#define BM 128

typedef __bf16 bf16x8 __attribute__((ext_vector_type(8)));
typedef short  short8 __attribute__((ext_vector_type(8)));
typedef float  f32x4  __attribute__((ext_vector_type(4)));

__device__ __forceinline__ unsigned short f2bf(float f) {
    union { float f; uint32_t u; } v; v.f = f;
    uint32_t u = v.u;
    uint32_t r = u + 0x7FFFu + ((u >> 16) & 1u);
    return (unsigned short)(r >> 16);
}
__device__ __forceinline__ float bf2f(unsigned short s) {
    union { uint32_t u; float f; } v; v.u = ((uint32_t)s) << 16;
    return v.f;
}

// ---- K1: fused cc transpose->Xbf (bf16, full-line writes) + per-channel partial sums ----
__global__ __launch_bounds__(256) void k_xpmean(const float* __restrict__ cc,
                                               unsigned short* __restrict__ Xbf,
                                               float* __restrict__ part) {
    __shared__ unsigned short T[256 * 72];     // [pix][72], ch swizzled by (t&3)<<4
    int blk = blockIdx.x;                      // b*160 + ct*16 + pt
    int b = blk / 160, rr = blk % 160;
    int ct = rr >> 4, pt = rr & 15;
    int c0 = ct * 64, p0 = pt * 256;
    int t = threadIdx.x;
    const float* base = cc + ((size_t)b * CC + c0) * HWSZ + p0;

    // phase A: per-channel partial sums (4 threads per channel, deterministic)
    {
        int c = t >> 2, sub = t & 3;
        const float4* row = (const float4*)(base + (size_t)c * HWSZ + sub * 64);
        float s = 0.f;
        #pragma unroll
        for (int k = 0; k < 16; k++) {
            float4 v = row[k];
            s += v.x + v.y + v.z + v.w;
        }
        s += __shfl_xor(s, 1);
        s += __shfl_xor(s, 2);
        if (sub == 0) part[((size_t)b * CC + c0 + c) * 16 + pt] = s;
    }

    // phase B: stage bf16 transposed tile (L2-hot re-read)
    for (int c = 0; c < 64; c++) {
        float v = base[(size_t)c * HWSZ + t];
        T[t * 72 + (c ^ ((t & 3) << 4))] = f2bf(v);
    }
    __syncthreads();
    // phase C: each thread writes its pixel's 64-ch chunk = 128 B full line
    unsigned short* dst = Xbf + ((size_t)b * HWSZ + p0 + t) * KX + c0;
    #pragma unroll
    for (int ch8 = 0; ch8 < 8; ch8++) {
        short8 v = *(short8*)&T[t * 72 + ((ch8 * 8) ^ ((t & 3) << 4))];
        *(short8*)&dst[ch8 * 8] = v;
    }
}

// ---- K2: merged Wg->bf16 cast (blocks 0..399) + xm partial-reduce (blocks 400..419) ----
__global__ void k_wbfxm(const float* __restrict__ Wg, unsigned short* __restrict__ Wbf,
                        const float* __restrict__ part, float* __restrict__ xm) {
    int blk = blockIdx.x;
    if (blk < 400) {
        int i = (blk * 256 + threadIdx.x) * 8;
        short8 o;
        #pragma unroll
        for (int j = 0; j < 8; j++) o[j] = (short)f2bf(Wg[i + j]);
        *(short8*)&Wbf[i] = o;
    } else {
        int i = (blk - 400) * 256 + threadIdx.x;   // 0..5119
        float s = 0.f;
        #pragma unroll
        for (int k = 0; k < 16; k++) s += part[(size_t)i * 16 + k];
        xm[i] = s * (1.f / HWSZ);
    }
}

// ---- K3: fused query + norms/sims/top2/softmax (one block per batch) ----
__global__ void k_attn3(const float* __restrict__ xm, const float* __restrict__ Wq,
                        const float* __restrict__ bq, const float* __restrict__ mk,
                        float* __restrict__ attnw, int* __restrict__ topidx) {
    int b = blockIdx.x;
    int t = threadIdx.x, lane = t & 63, wid = t >> 6;
    __shared__ float q[KD];
    const float* xr = xm + b * CC;
    for (int j = wid; j < KD; j += 4) {
        const float* wr = Wq + (size_t)j * CC;
        float p = 0.f;
        #pragma unroll
        for (int i = 0; i < CC / 64; i++) {
            int kk = lane + i * 64;
            p += xr[kk] * wr[kk];
        }
        #pragma unroll
        for (int off = 32; off; off >>= 1) p += __shfl_down(p, off);
        if (lane == 0) q[j] = p + bq[j];
    }
    __syncthreads();
    if (wid == 0) {
        float qv[3];
        float s = 0.f;
        #pragma unroll
        for (int i = 0; i < 3; i++) {
            int idx = lane + i * 64;
            qv[i] = (idx < KD) ? q[idx] : 0.f;
            s += qv[i] * qv[i];
        }
        #pragma unroll
        for (int off = 32; off; off >>= 1) s += __shfl_xor(s, off);
        float qn = fmaxf(sqrtf(s), 1e-12f);
        float sims[RR];
        #pragma unroll
        for (int r = 0; r < RR; r++) {
            float d = 0.f, kn2 = 0.f;
            #pragma unroll
            for (int i = 0; i < 3; i++) {
                int idx = lane + i * 64;
                float m = (idx < KD) ? mk[r * KD + idx] : 0.f;
                d += qv[i] * m;
                kn2 += m * m;
            }
            #pragma unroll
            for (int off = 32; off; off >>= 1) {
                d += __shfl_xor(d, off);
                kn2 += __shfl_xor(kn2, off);
            }
            sims[r] = d / (qn * fmaxf(sqrtf(kn2), 1e-12f));
        }
        if (lane == 0) {
            int i1 = 0;
            for (int r = 1; r < RR; r++) if (sims[r] > sims[i1]) i1 = r;
            int i2 = -1;
            for (int r = 0; r < RR; r++) { if (r == i1) continue; if (i2 < 0 || sims[r] > sims[i2]) i2 = r; }
            float e2 = expf((sims[i2] - sims[i1]) / TEMP);
            float a1 = 1.f / (1.f + e2);
            attnw[b * 2 + 0] = a1;
            attnw[b * 2 + 1] = e2 * a1;
            topidx[b * 2 + 0] = i1;
            topidx[b * 2 + 1] = i2;
        }
    }
}

// ---- K4: low-res combine only: comb[b][ch][256] bf16 + combT[b*256+yx][640] ----
__global__ void k_wref8(const float* __restrict__ vc, const float* __restrict__ attnw,
                        const int* __restrict__ topidx, unsigned short* __restrict__ comb,
                        unsigned short* __restrict__ combT) {
    int blk = blockIdx.x;                      // b*80 + c8
    int b = blk / 80, c8 = blk % 80;
    int c0 = c8 * 8;
    int t = threadIdx.x;                       // yx
    __shared__ unsigned short S[256 * 8];
    int i1 = topidx[b * 2], i2 = topidx[b * 2 + 1];
    float a1 = attnw[b * 2], a2 = attnw[b * 2 + 1];
    const float* p1 = vc + ((size_t)(i1 * BB + b) * CC + c0) * 256;
    const float* p2 = vc + ((size_t)(i2 * BB + b) * CC + c0) * 256;
    #pragma unroll
    for (int j = 0; j < 8; j++) {
        float v = a1 * p1[j * 256 + t] + a2 * p2[j * 256 + t];
        unsigned short us = f2bf(v);
        comb[((size_t)b * CC + c0 + j) * 256 + t] = us;
        S[t * 8 + j] = us;
    }
    __syncthreads();
    short8 o = *(short8*)&S[t * 8];
    *(short8*)&combT[((size_t)((b << 8) + t)) * KX + c0] = o;
}

// ---- K4c: low-res gate GEMM, BK=128 (5 K-iters, mirrors k_gemm staging) ----
__global__ __launch_bounds__(256) void k_gemmlow(
    const unsigned short* __restrict__ Wbf,   // [CC][KW], W2 at col offset 640
    const unsigned short* __restrict__ combT, // [B*256][640]
    unsigned short* __restrict__ glow)        // [BB][CC][256]
{
    __shared__ unsigned short Wt[128 * 128];  // 32 KB
    __shared__ unsigned short Xt[64 * 128];   // 16 KB

    const int t = threadIdx.x;
    const int lane = t & 63;
    const int w = t >> 6;
    const int mt = blockIdx.x;
    const int n0 = blockIdx.y * 64;
    const int b = n0 >> 8;
    const int yx0 = n0 & 255;
    const int mbase = mt * BM;

    f32x4 acc[4][2];
    #pragma unroll
    for (int i = 0; i < 4; i++)
        #pragma unroll
        for (int j = 0; j < 2; j++) acc[i][j] = (f32x4){0.f, 0.f, 0.f, 0.f};

    const int wm = (w >> 1) * 64;
    const int wn = (w & 1) * 32;
    const int lrow = lane & 15;
    const int lkoff = (lane >> 4) * 8;

    const int srow = t >> 4;                   // 0..15
    const int soct = (t & 15) ^ srow;          // 16 chunks/row swizzle

    const unsigned short* wsrc0 = Wbf + (size_t)mbase * KW + CC;   // W2 half
    const unsigned short* xsrc0 = combT + (size_t)n0 * KX;

    for (int ks = 0; ks < 5; ks++) {
        const int kb = ks * 128;
        if (ks) __syncthreads();
        #pragma unroll
        for (int i = 0; i < 8; i++) {
            const unsigned short* gw = wsrc0 + (size_t)(i * 16 + srow) * KW + kb + soct * 8;
            unsigned short* lw = &Wt[(i * 256 + (t & ~63)) * 8];
            __builtin_amdgcn_global_load_lds((const __attribute__((address_space(1))) void*)gw,
                                             (__attribute__((address_space(3))) void*)lw, 16, 0, 0);
        }
        #pragma unroll
        for (int i = 0; i < 4; i++) {
            const unsigned short* gx = xsrc0 + (size_t)(i * 16 + srow) * KX + kb + soct * 8;
            unsigned short* lx = &Xt[(i * 256 + (t & ~63)) * 8];
            __builtin_amdgcn_global_load_lds((const __attribute__((address_space(1))) void*)gx,
                                             (__attribute__((address_space(3))) void*)lx, 16, 0, 0);
        }
        __syncthreads();

        #pragma unroll
        for (int ki = 0; ki < 4; ki++) {
            bf16x8 af[4], bfr[2];
            const int kk = ki * 32 + lkoff;
            #pragma unroll
            for (int mi = 0; mi < 4; mi++) {
                int row = wm + mi * 16 + lrow;
                af[mi] = *(const bf16x8*)&Wt[row * 128 + (kk ^ (lrow << 3))];
            }
            #pragma unroll
            for (int ni = 0; ni < 2; ni++) {
                int prow = wn + ni * 16 + lrow;
                bfr[ni] = *(const bf16x8*)&Xt[prow * 128 + (kk ^ (lrow << 3))];
            }
            #pragma unroll
            for (int mi = 0; mi < 4; mi++)
                #pragma unroll
                for (int ni = 0; ni < 2; ni++)
                    acc[mi][ni] = __builtin_amdgcn_mfma_f32_16x16x32_bf16(af[mi], bfr[ni], acc[mi][ni], 0, 0, 0);
        }
    }

    #pragma unroll
    for (int mi = 0; mi < 4; mi++) {
        #pragma unroll
        for (int r = 0; r < 4; r++) {
            int ch = mbase + wm + mi * 16 + (lane >> 4) * 4 + r;
            #pragma unroll
            for (int ni = 0; ni < 2; ni++) {
                int yx = yx0 + wn + ni * 16 + (lane & 15);
                glow[(((size_t)b * CC + ch) << 8) + yx] = f2bf(acc[mi][ni][r]);
            }
        }
    }
}

// ---- K5: main GEMM (W1 @ cc), BK=128 / BN=64 (R13-proven), LDS-lerp epilogue ----
__global__ __launch_bounds__(256) void k_gemm(
    const unsigned short* __restrict__ Wbf,   // [CC][KW], W1 at col 0
    const unsigned short* __restrict__ Xbf,   // [BB][HWSZ][640]
    const float* __restrict__ cc,             // [BB][CC][HWSZ]
    const unsigned short* __restrict__ comb,  // [BB][CC][256]
    const unsigned short* __restrict__ glow,  // [BB][CC][256]
    const float* __restrict__ bg,             // [CC]
    float* __restrict__ out)                  // [BB][CC][HWSZ]
{
    __shared__ unsigned short SM[128 * 128 + 64 * 128];  // 48 KB, reused by epilogue
    unsigned short* Wt = SM;                  // [128 rows][128 k], chunk-XOR by (row&15)
    unsigned short* Xt = SM + 128 * 128;      // [64 rows][128 k]

    const int t = threadIdx.x;
    const int lane = t & 63;
    const int w = t >> 6;

    // XCD-chunked bijective swizzle: 2560 blocks, 8 XCDs, 320 per XCD (one batch each)
    const int orig = blockIdx.x;
    const int bid = (orig & 7) * 320 + (orig >> 3);
    const int mt = bid % 5;
    const int nt = (bid / 5) % 64;             // = output row y (BN=64 = full row)
    const int b = bid / 320;
    const int mbase = mt * BM;
    const int hwbase = nt * 64;

    f32x4 acc[4][2];
    #pragma unroll
    for (int i = 0; i < 4; i++)
        #pragma unroll
        for (int j = 0; j < 2; j++) acc[i][j] = (f32x4){0.f, 0.f, 0.f, 0.f};

    const int wm = (w >> 1) * 64;
    const int wn = (w & 1) * 32;
    const int lrow = lane & 15;
    const int lkoff = (lane >> 4) * 8;

    const int srow = t >> 4;                   // 0..15: row within 16-row staging slab
    const int soct = (t & 15) ^ srow;          // pre-swizzled source chunk (16 chunks/row)

    const unsigned short* wsrc0 = Wbf + (size_t)mbase * KW;
    const unsigned short* xsrc0 = Xbf + ((size_t)b * HWSZ + hwbase) * KX;

    for (int ks = 0; ks < 5; ks++) {           // KX/128
        const int kb = ks * 128;
        if (ks) __syncthreads();
        // W tile: 128 rows x 16 chunks = 2048 chunks, 8 passes
        #pragma unroll
        for (int i = 0; i < 8; i++) {
            const unsigned short* gw = wsrc0 + (size_t)(i * 16 + srow) * KW + kb + soct * 8;
            unsigned short* lw = &Wt[(i * 256 + (t & ~63)) * 8];
            __builtin_amdgcn_global_load_lds((const __attribute__((address_space(1))) void*)gw,
                                             (__attribute__((address_space(3))) void*)lw, 16, 0, 0);
        }
        // X tile: 64 rows x 16 chunks = 1024 chunks, 4 passes
        #pragma unroll
        for (int i = 0; i < 4; i++) {
            const unsigned short* gx = xsrc0 + (size_t)(i * 16 + srow) * KX + kb + soct * 8;
            unsigned short* lx = &Xt[(i * 256 + (t & ~63)) * 8];
            __builtin_amdgcn_global_load_lds((const __attribute__((address_space(1))) void*)gx,
                                             (__attribute__((address_space(3))) void*)lx, 16, 0, 0);
        }
        __syncthreads();

        #pragma unroll
        for (int ki = 0; ki < 4; ki++) {       // 128 k / 32
            bf16x8 af[4], bfr[2];
            const int kk = ki * 32 + lkoff;
            #pragma unroll
            for (int mi = 0; mi < 4; mi++) {
                int row = wm + mi * 16 + lrow;      // row & 15 == lrow
                af[mi] = *(const bf16x8*)&Wt[row * 128 + (kk ^ (lrow << 3))];
            }
            #pragma unroll
            for (int ni = 0; ni < 2; ni++) {
                int prow = wn + ni * 16 + lrow;
                bfr[ni] = *(const bf16x8*)&Xt[prow * 128 + (kk ^ (lrow << 3))];
            }
            #pragma unroll
            for (int mi = 0; mi < 4; mi++)
                #pragma unroll
                for (int ni = 0; ni < 2; ni++)
                    acc[mi][ni] = __builtin_amdgcn_mfma_f32_16x16x32_bf16(af[mi], bfr[ni], acc[mi][ni], 0, 0, 0);
        }
    }

    // --- epilogue: stage y-lerped glow/comb rows (block-uniform y), then x-lerp per lane
    __syncthreads();                           // all waves done reading Wt/Xt
    float* gy = (float*)SM;                    // [128][17] fp32 = 8704 B (bg folded in)
    float* cy = gy + 128 * 17;                 // +8704 = 17408 B total
    {
        float py = nt * 0.25f - 0.375f;
        int iy = (int)floorf(py);
        float fy = py - (float)iy;
        int y0 = max(iy, 0), y1 = min(iy + 1, VH - 1);
        const unsigned short* gb = glow + (((size_t)b * CC + mbase) << 8);
        const unsigned short* cb = comb + (((size_t)b * CC + mbase) << 8);
        #pragma unroll
        for (int i = 0; i < 8; i++) {
            int e = t + i * 256;
            int chl = e >> 4, x16 = e & 15;
            size_t base = ((size_t)chl << 8);
            float g0 = bf2f(gb[base + y0 * 16 + x16]);
            float g1 = bf2f(gb[base + y1 * 16 + x16]);
            gy[chl * 17 + x16] = g0 + fy * (g1 - g0) + bg[mbase + chl];
            float c0v = bf2f(cb[base + y0 * 16 + x16]);
            float c1v = bf2f(cb[base + y1 * 16 + x16]);
            cy[chl * 17 + x16] = c0v + fy * (c1v - c0v);
        }
    }
    __syncthreads();

    float fxv[2]; int x0i[2], x1i[2];
    #pragma unroll
    for (int ni = 0; ni < 2; ni++) {
        int x = wn + ni * 16 + lrow;
        float pxx = x * 0.25f - 0.375f;
        int ix = (int)floorf(pxx);
        fxv[ni] = pxx - (float)ix;
        x0i[ni] = max(ix, 0);
        x1i[ni] = min(ix + 1, VW - 1);
    }

    const size_t pb = (size_t)b * CC * HWSZ;
    #pragma unroll
    for (int mi = 0; mi < 4; mi++) {
        #pragma unroll
        for (int r = 0; r < 4; r++) {
            int chl = wm + mi * 16 + (lane >> 4) * 4 + r;
            int ch = mbase + chl;
            size_t rowoff = pb + (size_t)ch * HWSZ;
            #pragma unroll
            for (int ni = 0; ni < 2; ni++) {
                int pix = hwbase + wn + ni * 16 + lrow;
                float g0 = gy[chl * 17 + x0i[ni]];
                float g1 = gy[chl * 17 + x1i[ni]];
                float gv = g0 + fxv[ni] * (g1 - g0);
                float w0 = cy[chl * 17 + x0i[ni]];
                float w1 = cy[chl * 17 + x1i[ni]];
                float wv = w0 + fxv[ni] * (w1 - w0);
                float gp = acc[mi][ni][r] + gv;         // bg folded into gy
                float ex = __expf(-gp);                 // fast v_exp_f32 path
                float g = __fdividef(1.f, 1.f + ex);    // fast v_rcp_f32 path
                float cv = cc[rowoff + pix];
                out[rowoff + pix] = cv + g * (wv - cv);
            }
        }
    }
}

extern "C" void kernel_launch(void* const* d_in, const int* in_sizes, int n_in,
                              void* d_out, int out_size, void* d_ws, size_t ws_size,
                              hipStream_t stream) {
    const float* cc = (const float*)d_in[0];
    const float* Wq = (const float*)d_in[1];
    const float* bq = (const float*)d_in[2];
    const float* mk = (const float*)d_in[3];
    const float* vc = (const float*)d_in[4];
    const float* Wg = (const float*)d_in[5];
    const float* bg = (const float*)d_in[6];
    float* out = (float*)d_out;

    char* ws = (char*)d_ws;
    float* xm             = (float*)ws;                        // 20480
    float* attnw          = (float*)(ws + 20480);              // 64
    int*   topidx         = (int*)(ws + 20544);                // 64
    float* part           = (float*)(ws + 25728);              // 327680 -> 353408
    unsigned short* Wbf   = (unsigned short*)(ws + 353408);    // 1638400 -> 1991808
    unsigned short* Xbf   = (unsigned short*)(ws + 1991808);   // 41943040 -> 43934848
    unsigned short* comb  = (unsigned short*)(ws + 43934848);  // 2621440 -> 46556288
    unsigned short* combT = (unsigned short*)(ws + 46556288);  // 2621440 -> 49177728
    unsigned short* glow  = (unsigned short*)(ws + 49177728);  // 2621440 -> 51799168

    k_xpmean<<<BB * 160, 256, 0, stream>>>(cc, Xbf, part);
    k_wbfxm<<<420, 256, 0, stream>>>(Wg, Wbf, part, xm);
    k_attn3<<<BB, 256, 0, stream>>>(xm, Wq, bq, mk, attnw, topidx);
    k_wref8<<<BB * 80, 256, 0, stream>>>(vc, attnw, topidx, comb, combT);
    dim3 gl(5, (BB * 256) / 64);
    k_gemmlow<<<gl, 256, 0, stream>>>(Wbf, combT, glow);
    k_gemm<<<2560, 256, 0, stream>>>(Wbf, Xbf, cc, comb, glow, bg, out);
}

// Round 16
// 118.849 us; speedup vs baseline: 1.2158x; 1.2158x over previous
//
#include <hip/hip_runtime.h>
#include <hip/hip_bf16.h>
#include <stdint.h>

#define BB 8
#define CC 640
#define HWSZ 4096
#define RR 4
#define KD 160
#define VH 16
#define VW 16
#define KW 1280      // Wbf row stride (full Wg row)
#define KX 640       // GEMM K (W1 half)
#define TEMP 0.1f

#define BM 128

typedef __bf16 bf16x8 __attribute__((ext_vector_type(8)));
typedef short  short8 __attribute__((ext_vector_type(8)));
typedef float  f32x4  __attribute__((ext_vector_type(4)));

__device__ __forceinline__ unsigned short f2bf(float f) {
    union { float f; uint32_t u; } v; v.f = f;
    uint32_t u = v.u;
    uint32_t r = u + 0x7FFFu + ((u >> 16) & 1u);
    return (unsigned short)(r >> 16);
}
__device__ __forceinline__ float bf2f(unsigned short s) {
    union { uint32_t u; float f; } v; v.u = ((uint32_t)s) << 16;
    return v.f;
}

// ---- K1: fused cc transpose->Xbf (bf16, full-line writes) + per-channel partial sums ----
__global__ __launch_bounds__(256) void k_xpmean(const float* __restrict__ cc,
                                               unsigned short* __restrict__ Xbf,
                                               float* __restrict__ part) {
    __shared__ unsigned short T[256 * 72];     // [pix][72], ch swizzled by (t&3)<<4
    int blk = blockIdx.x;                      // b*160 + ct*16 + pt
    int b = blk / 160, rr = blk % 160;
    int ct = rr >> 4, pt = rr & 15;
    int c0 = ct * 64, p0 = pt * 256;
    int t = threadIdx.x;
    const float* base = cc + ((size_t)b * CC + c0) * HWSZ + p0;

    // phase A: per-channel partial sums (4 threads per channel, deterministic)
    {
        int c = t >> 2, sub = t & 3;
        const float4* row = (const float4*)(base + (size_t)c * HWSZ + sub * 64);
        float s = 0.f;
        #pragma unroll
        for (int k = 0; k < 16; k++) {
            float4 v = row[k];
            s += v.x + v.y + v.z + v.w;
        }
        s += __shfl_xor(s, 1);
        s += __shfl_xor(s, 2);
        if (sub == 0) part[((size_t)b * CC + c0 + c) * 16 + pt] = s;
    }

    // phase B: stage bf16 transposed tile (L2-hot re-read)
    for (int c = 0; c < 64; c++) {
        float v = base[(size_t)c * HWSZ + t];
        T[t * 72 + (c ^ ((t & 3) << 4))] = f2bf(v);
    }
    __syncthreads();
    // phase C: each thread writes its pixel's 64-ch chunk = 128 B full line
    unsigned short* dst = Xbf + ((size_t)b * HWSZ + p0 + t) * KX + c0;
    #pragma unroll
    for (int ch8 = 0; ch8 < 8; ch8++) {
        short8 v = *(short8*)&T[t * 72 + ((ch8 * 8) ^ ((t & 3) << 4))];
        *(short8*)&dst[ch8 * 8] = v;
    }
}

// ---- K2: merged Wg->bf16 cast (blocks 0..399) + xm partial-reduce (blocks 400..419) ----
__global__ void k_wbfxm(const float* __restrict__ Wg, unsigned short* __restrict__ Wbf,
                        const float* __restrict__ part, float* __restrict__ xm) {
    int blk = blockIdx.x;
    if (blk < 400) {
        int i = (blk * 256 + threadIdx.x) * 8;
        short8 o;
        #pragma unroll
        for (int j = 0; j < 8; j++) o[j] = (short)f2bf(Wg[i + j]);
        *(short8*)&Wbf[i] = o;
    } else {
        int i = (blk - 400) * 256 + threadIdx.x;   // 0..5119
        float s = 0.f;
        #pragma unroll
        for (int k = 0; k < 16; k++) s += part[(size_t)i * 16 + k];
        xm[i] = s * (1.f / HWSZ);
    }
}

// ---- K3a: query = xm @ Wq.T + bq  (one wave per output; R13-proven) ----
__global__ void k_query(const float* __restrict__ xm, const float* __restrict__ Wq,
                        const float* __restrict__ bq, float* __restrict__ q) {
    int o = blockIdx.x;                        // b*KD + j
    int b = o / KD, j = o % KD;
    int lane = threadIdx.x;
    const float* xr = xm + b * CC;
    const float* wr = Wq + (size_t)j * CC;
    float p = 0.f;
    #pragma unroll
    for (int i = 0; i < CC / 64; i++) {
        int kk = lane + i * 64;
        p += xr[kk] * wr[kk];
    }
    #pragma unroll
    for (int off = 32; off; off >>= 1) p += __shfl_down(p, off);
    if (lane == 0) q[o] = p + bq[j];
}

// ---- K3b: norms / sims / top2 / softmax (wave per batch; R13-proven) ----
__global__ void k_attn2(const float* __restrict__ q, const float* __restrict__ mk,
                        float* __restrict__ attnw, int* __restrict__ topidx) {
    int t = threadIdx.x, lane = t & 63, b = t >> 6;
    __shared__ float smk[RR * KD];
    for (int i = t; i < RR * KD; i += 512) smk[i] = mk[i];
    __syncthreads();
    const float* qr = q + b * KD;
    float qv[3];
    float s = 0.f;
    #pragma unroll
    for (int i = 0; i < 3; i++) {
        int idx = lane + i * 64;
        qv[i] = (idx < KD) ? qr[idx] : 0.f;
        s += qv[i] * qv[i];
    }
    #pragma unroll
    for (int off = 32; off; off >>= 1) s += __shfl_xor(s, off);
    float qn = fmaxf(sqrtf(s), 1e-12f);
    float sims[RR];
    #pragma unroll
    for (int r = 0; r < RR; r++) {
        float d = 0.f, kn2 = 0.f;
        #pragma unroll
        for (int i = 0; i < 3; i++) {
            int idx = lane + i * 64;
            float m = (idx < KD) ? smk[r * KD + idx] : 0.f;
            d += qv[i] * m;
            kn2 += m * m;
        }
        #pragma unroll
        for (int off = 32; off; off >>= 1) {
            d += __shfl_xor(d, off);
            kn2 += __shfl_xor(kn2, off);
        }
        sims[r] = d / (qn * fmaxf(sqrtf(kn2), 1e-12f));
    }
    if (lane == 0) {
        int i1 = 0;
        for (int r = 1; r < RR; r++) if (sims[r] > sims[i1]) i1 = r;
        int i2 = -1;
        for (int r = 0; r < RR; r++) { if (r == i1) continue; if (i2 < 0 || sims[r] > sims[i2]) i2 = r; }
        float e2 = expf((sims[i2] - sims[i1]) / TEMP);
        float a1 = 1.f / (1.f + e2);
        attnw[b * 2 + 0] = a1;
        attnw[b * 2 + 1] = e2 * a1;
        topidx[b * 2 + 0] = i1;
        topidx[b * 2 + 1] = i2;
    }
}

// ---- K4: low-res combine only: comb[b][ch][256] bf16 + combT[b*256+yx][640] ----
__global__ void k_wref8(const float* __restrict__ vc, const float* __restrict__ attnw,
                        const int* __restrict__ topidx, unsigned short* __restrict__ comb,
                        unsigned short* __restrict__ combT) {
    int blk = blockIdx.x;                      // b*80 + c8
    int b = blk / 80, c8 = blk % 80;
    int c0 = c8 * 8;
    int t = threadIdx.x;                       // yx
    __shared__ unsigned short S[256 * 8];
    int i1 = topidx[b * 2], i2 = topidx[b * 2 + 1];
    float a1 = attnw[b * 2], a2 = attnw[b * 2 + 1];
    const float* p1 = vc + ((size_t)(i1 * BB + b) * CC + c0) * 256;
    const float* p2 = vc + ((size_t)(i2 * BB + b) * CC + c0) * 256;
    #pragma unroll
    for (int j = 0; j < 8; j++) {
        float v = a1 * p1[j * 256 + t] + a2 * p2[j * 256 + t];
        unsigned short us = f2bf(v);
        comb[((size_t)b * CC + c0 + j) * 256 + t] = us;
        S[t * 8 + j] = us;
    }
    __syncthreads();
    short8 o = *(short8*)&S[t * 8];
    *(short8*)&combT[((size_t)((b << 8) + t)) * KX + c0] = o;
}

// ---- K4c: low-res gate GEMM, BK=128 (5 K-iters, mirrors k_gemm staging) ----
__global__ __launch_bounds__(256) void k_gemmlow(
    const unsigned short* __restrict__ Wbf,   // [CC][KW], W2 at col offset 640
    const unsigned short* __restrict__ combT, // [B*256][640]
    unsigned short* __restrict__ glow)        // [BB][CC][256]
{
    __shared__ unsigned short Wt[128 * 128];  // 32 KB
    __shared__ unsigned short Xt[64 * 128];   // 16 KB

    const int t = threadIdx.x;
    const int lane = t & 63;
    const int w = t >> 6;
    const int mt = blockIdx.x;
    const int n0 = blockIdx.y * 64;
    const int b = n0 >> 8;
    const int yx0 = n0 & 255;
    const int mbase = mt * BM;

    f32x4 acc[4][2];
    #pragma unroll
    for (int i = 0; i < 4; i++)
        #pragma unroll
        for (int j = 0; j < 2; j++) acc[i][j] = (f32x4){0.f, 0.f, 0.f, 0.f};

    const int wm = (w >> 1) * 64;
    const int wn = (w & 1) * 32;
    const int lrow = lane & 15;
    const int lkoff = (lane >> 4) * 8;

    const int srow = t >> 4;                   // 0..15
    const int soct = (t & 15) ^ srow;          // 16 chunks/row swizzle

    const unsigned short* wsrc0 = Wbf + (size_t)mbase * KW + CC;   // W2 half
    const unsigned short* xsrc0 = combT + (size_t)n0 * KX;

    for (int ks = 0; ks < 5; ks++) {
        const int kb = ks * 128;
        if (ks) __syncthreads();
        #pragma unroll
        for (int i = 0; i < 8; i++) {
            const unsigned short* gw = wsrc0 + (size_t)(i * 16 + srow) * KW + kb + soct * 8;
            unsigned short* lw = &Wt[(i * 256 + (t & ~63)) * 8];
            __builtin_amdgcn_global_load_lds((const __attribute__((address_space(1))) void*)gw,
                                             (__attribute__((address_space(3))) void*)lw, 16, 0, 0);
        }
        #pragma unroll
        for (int i = 0; i < 4; i++) {
            const unsigned short* gx = xsrc0 + (size_t)(i * 16 + srow) * KX + kb + soct * 8;
            unsigned short* lx = &Xt[(i * 256 + (t & ~63)) * 8];
            __builtin_amdgcn_global_load_lds((const __attribute__((address_space(1))) void*)gx,
                                             (__attribute__((address_space(3))) void*)lx, 16, 0, 0);
        }
        __syncthreads();

        #pragma unroll
        for (int ki = 0; ki < 4; ki++) {
            bf16x8 af[4], bfr[2];
            const int kk = ki * 32 + lkoff;
            #pragma unroll
            for (int mi = 0; mi < 4; mi++) {
                int row = wm + mi * 16 + lrow;
                af[mi] = *(const bf16x8*)&Wt[row * 128 + (kk ^ (lrow << 3))];
            }
            #pragma unroll
            for (int ni = 0; ni < 2; ni++) {
                int prow = wn + ni * 16 + lrow;
                bfr[ni] = *(const bf16x8*)&Xt[prow * 128 + (kk ^ (lrow << 3))];
            }
            #pragma unroll
            for (int mi = 0; mi < 4; mi++)
                #pragma unroll
                for (int ni = 0; ni < 2; ni++)
                    acc[mi][ni] = __builtin_amdgcn_mfma_f32_16x16x32_bf16(af[mi], bfr[ni], acc[mi][ni], 0, 0, 0);
        }
    }

    #pragma unroll
    for (int mi = 0; mi < 4; mi++) {
        #pragma unroll
        for (int r = 0; r < 4; r++) {
            int ch = mbase + wm + mi * 16 + (lane >> 4) * 4 + r;
            #pragma unroll
            for (int ni = 0; ni < 2; ni++) {
                int yx = yx0 + wn + ni * 16 + (lane & 15);
                glow[(((size_t)b * CC + ch) << 8) + yx] = f2bf(acc[mi][ni][r]);
            }
        }
    }
}

// ---- K5: main GEMM (W1 @ cc), BK=128 / BN=64 (R13-proven), LDS-lerp epilogue ----
__global__ __launch_bounds__(256) void k_gemm(
    const unsigned short* __restrict__ Wbf,   // [CC][KW], W1 at col 0
    const unsigned short* __restrict__ Xbf,   // [BB][HWSZ][640]
    const float* __restrict__ cc,             // [BB][CC][HWSZ]
    const unsigned short* __restrict__ comb,  // [BB][CC][256]
    const unsigned short* __restrict__ glow,  // [BB][CC][256]
    const float* __restrict__ bg,             // [CC]
    float* __restrict__ out)                  // [BB][CC][HWSZ]
{
    __shared__ unsigned short SM[128 * 128 + 64 * 128];  // 48 KB, reused by epilogue
    unsigned short* Wt = SM;                  // [128 rows][128 k], chunk-XOR by (row&15)
    unsigned short* Xt = SM + 128 * 128;      // [64 rows][128 k]

    const int t = threadIdx.x;
    const int lane = t & 63;
    const int w = t >> 6;

    // XCD-chunked bijective swizzle: 2560 blocks, 8 XCDs, 320 per XCD (one batch each)
    const int orig = blockIdx.x;
    const int bid = (orig & 7) * 320 + (orig >> 3);
    const int mt = bid % 5;
    const int nt = (bid / 5) % 64;             // = output row y (BN=64 = full row)
    const int b = bid / 320;
    const int mbase = mt * BM;
    const int hwbase = nt * 64;

    f32x4 acc[4][2];
    #pragma unroll
    for (int i = 0; i < 4; i++)
        #pragma unroll
        for (int j = 0; j < 2; j++) acc[i][j] = (f32x4){0.f, 0.f, 0.f, 0.f};

    const int wm = (w >> 1) * 64;
    const int wn = (w & 1) * 32;
    const int lrow = lane & 15;
    const int lkoff = (lane >> 4) * 8;

    const int srow = t >> 4;                   // 0..15: row within 16-row staging slab
    const int soct = (t & 15) ^ srow;          // pre-swizzled source chunk (16 chunks/row)

    const unsigned short* wsrc0 = Wbf + (size_t)mbase * KW;
    const unsigned short* xsrc0 = Xbf + ((size_t)b * HWSZ + hwbase) * KX;

    for (int ks = 0; ks < 5; ks++) {           // KX/128
        const int kb = ks * 128;
        if (ks) __syncthreads();
        // W tile: 128 rows x 16 chunks = 2048 chunks, 8 passes
        #pragma unroll
        for (int i = 0; i < 8; i++) {
            const unsigned short* gw = wsrc0 + (size_t)(i * 16 + srow) * KW + kb + soct * 8;
            unsigned short* lw = &Wt[(i * 256 + (t & ~63)) * 8];
            __builtin_amdgcn_global_load_lds((const __attribute__((address_space(1))) void*)gw,
                                             (__attribute__((address_space(3))) void*)lw, 16, 0, 0);
        }
        // X tile: 64 rows x 16 chunks = 1024 chunks, 4 passes
        #pragma unroll
        for (int i = 0; i < 4; i++) {
            const unsigned short* gx = xsrc0 + (size_t)(i * 16 + srow) * KX + kb + soct * 8;
            unsigned short* lx = &Xt[(i * 256 + (t & ~63)) * 8];
            __builtin_amdgcn_global_load_lds((const __attribute__((address_space(1))) void*)gx,
                                             (__attribute__((address_space(3))) void*)lx, 16, 0, 0);
        }
        __syncthreads();

        #pragma unroll
        for (int ki = 0; ki < 4; ki++) {       // 128 k / 32
            bf16x8 af[4], bfr[2];
            const int kk = ki * 32 + lkoff;
            #pragma unroll
            for (int mi = 0; mi < 4; mi++) {
                int row = wm + mi * 16 + lrow;      // row & 15 == lrow
                af[mi] = *(const bf16x8*)&Wt[row * 128 + (kk ^ (lrow << 3))];
            }
            #pragma unroll
            for (int ni = 0; ni < 2; ni++) {
                int prow = wn + ni * 16 + lrow;
                bfr[ni] = *(const bf16x8*)&Xt[prow * 128 + (kk ^ (lrow << 3))];
            }
            #pragma unroll
            for (int mi = 0; mi < 4; mi++)
                #pragma unroll
                for (int ni = 0; ni < 2; ni++)
                    acc[mi][ni] = __builtin_amdgcn_mfma_f32_16x16x32_bf16(af[mi], bfr[ni], acc[mi][ni], 0, 0, 0);
        }
    }

    // --- epilogue: stage y-lerped glow/comb rows (block-uniform y), then x-lerp per lane
    __syncthreads();                           // all waves done reading Wt/Xt
    float* gy = (float*)SM;                    // [128][17] fp32 = 8704 B (bg folded in)
    float* cy = gy + 128 * 17;                 // +8704 = 17408 B total
    {
        float py = nt * 0.25f - 0.375f;
        int iy = (int)floorf(py);
        float fy = py - (float)iy;
        int y0 = max(iy, 0), y1 = min(iy + 1, VH - 1);
        const unsigned short* gb = glow + (((size_t)b * CC + mbase) << 8);
        const unsigned short* cb = comb + (((size_t)b * CC + mbase) << 8);
        #pragma unroll
        for (int i = 0; i < 8; i++) {
            int e = t + i * 256;
            int chl = e >> 4, x16 = e & 15;
            size_t base = ((size_t)chl << 8);
            float g0 = bf2f(gb[base + y0 * 16 + x16]);
            float g1 = bf2f(gb[base + y1 * 16 + x16]);
            gy[chl * 17 + x16] = g0 + fy * (g1 - g0) + bg[mbase + chl];
            float c0v = bf2f(cb[base + y0 * 16 + x16]);
            float c1v = bf2f(cb[base + y1 * 16 + x16]);
            cy[chl * 17 + x16] = c0v + fy * (c1v - c0v);
        }
    }
    __syncthreads();

    float fxv[2]; int x0i[2], x1i[2];
    #pragma unroll
    for (int ni = 0; ni < 2; ni++) {
        int x = wn + ni * 16 + lrow;
        float pxx = x * 0.25f - 0.375f;
        int ix = (int)floorf(pxx);
        fxv[ni] = pxx - (float)ix;
        x0i[ni] = max(ix, 0);
        x1i[ni] = min(ix + 1, VW - 1);
    }

    const size_t pb = (size_t)b * CC * HWSZ;
    #pragma unroll
    for (int mi = 0; mi < 4; mi++) {
        #pragma unroll
        for (int r = 0; r < 4; r++) {
            int chl = wm + mi * 16 + (lane >> 4) * 4 + r;
            int ch = mbase + chl;
            size_t rowoff = pb + (size_t)ch * HWSZ;
            #pragma unroll
            for (int ni = 0; ni < 2; ni++) {
                int pix = hwbase + wn + ni * 16 + lrow;
                float g0 = gy[chl * 17 + x0i[ni]];
                float g1 = gy[chl * 17 + x1i[ni]];
                float gv = g0 + fxv[ni] * (g1 - g0);
                float w0 = cy[chl * 17 + x0i[ni]];
                float w1 = cy[chl * 17 + x1i[ni]];
                float wv = w0 + fxv[ni] * (w1 - w0);
                float gp = acc[mi][ni][r] + gv;         // bg folded into gy
                float ex = __expf(-gp);                 // fast v_exp_f32 path
                float g = __fdividef(1.f, 1.f + ex);    // fast v_rcp_f32 path
                float cv = cc[rowoff + pix];
                out[rowoff + pix] = cv + g * (wv - cv);
            }
        }
    }
}

extern "C" void kernel_launch(void* const* d_in, const int* in_sizes, int n_in,
                              void* d_out, int out_size, void* d_ws, size_t ws_size,
                              hipStream_t stream) {
    const float* cc = (const float*)d_in[0];
    const float* Wq = (const float*)d_in[1];
    const float* bq = (const float*)d_in[2];
    const float* mk = (const float*)d_in[3];
    const float* vc = (const float*)d_in[4];
    const float* Wg = (const float*)d_in[5];
    const float* bg = (const float*)d_in[6];
    float* out = (float*)d_out;

    char* ws = (char*)d_ws;
    float* xm             = (float*)ws;                        // 20480
    float* attnw          = (float*)(ws + 20480);              // 64
    int*   topidx         = (int*)(ws + 20544);                // 64
    float* q              = (float*)(ws + 20608);              // 5120  -> 25728
    float* part           = (float*)(ws + 25728);              // 327680 -> 353408
    unsigned short* Wbf   = (unsigned short*)(ws + 353408);    // 1638400 -> 1991808
    unsigned short* Xbf   = (unsigned short*)(ws + 1991808);   // 41943040 -> 43934848
    unsigned short* comb  = (unsigned short*)(ws + 43934848);  // 2621440 -> 46556288
    unsigned short* combT = (unsigned short*)(ws + 46556288);  // 2621440 -> 49177728
    unsigned short* glow  = (unsigned short*)(ws + 49177728);  // 2621440 -> 51799168

    k_xpmean<<<BB * 160, 256, 0, stream>>>(cc, Xbf, part);
    k_wbfxm<<<420, 256, 0, stream>>>(Wg, Wbf, part, xm);
    k_query<<<BB * KD, 64, 0, stream>>>(xm, Wq, bq, q);
    k_attn2<<<1, 512, 0, stream>>>(q, mk, attnw, topidx);
    k_wref8<<<BB * 80, 256, 0, stream>>>(vc, attnw, topidx, comb, combT);
    dim3 gl(5, (BB * 256) / 64);
    k_gemmlow<<<gl, 256, 0, stream>>>(Wbf, combT, glow);
    k_gemm<<<2560, 256, 0, stream>>>(Wbf, Xbf, cc, comb, glow, bg, out);
}